// Round 2
// baseline (547.163 us; speedup 1.0000x reference)
//
#include <hip/hip_runtime.h>
#include <hip/hip_bf16.h>

// Problem constants (B=1, C=512, T=4, H=W=32) — all tensors fp32
#define C_DIM 512
#define P_DIM 4096   // N*H*W = 4*32*32 ; pixel p = t*1024 + h*32 + w ; x flat = c*4096 + p
#define NH 8
#define DH 64
#define KS 7
#define KW 49

__device__ __forceinline__ float wave_sum(float v){
#pragma unroll
  for (int o = 32; o > 0; o >>= 1) v += __shfl_xor(v, o, 64);
  return v;
}
__device__ __forceinline__ float wave_max(float v){
#pragma unroll
  for (int o = 32; o > 0; o >>= 1) v = fmaxf(v, __shfl_xor(v, o, 64));
  return v;
}

// ---------------- K1: s[c] = 1 + sum_f cond[f]*norm_w[f][c] ----------------
__global__ __launch_bounds__(512) void k_prep_s(const float* __restrict__ cond,
                                                const float* __restrict__ norm_w,
                                                float* __restrict__ s){
  int c = threadIdx.x;            // 512 threads
  float acc = 0.f;
  for (int f = 0; f < 256; ++f)
    acc = fmaf(cond[f], norm_w[f * 512 + c], acc);
  s[c] = acc + 1.0f;
}

// ---------------- K2: rope cos/sin tables, indexed [(hw*8+hd)*16 + j] -------
__global__ __launch_bounds__(256) void k_tables(const float* __restrict__ pos,
                                                float* __restrict__ cos_t,
                                                float* __restrict__ sin_t){
  int idx = blockIdx.x * 256 + threadIdx.x;   // 131072 = 1024*8*16
  int j  = idx & 15;
  int hd = (idx >> 4) & 7;
  int hw = idx >> 7;
  int axis = j >> 3;
  int i = j & 7;
  // freqs[hd][i] = exp(ln(pi) + (i*8+hd)*ln(10)/64)
  const float LOG_PI = 1.1447298858494002f;
  const float LOG10F = 2.302585092994046f;
  float f = expf(LOG_PI + (float)(i * 8 + hd) * (LOG10F / 64.0f));
  float pv = pos[hw * 2 + axis];
  float th = pv * f;
  cos_t[idx] = cosf(th);
  sin_t[idx] = sinf(th);
}

// ---------------- K3: rms[p] = rsqrt(mean_c x^2 + eps) ---------------------
__global__ __launch_bounds__(256) void k_rms(const float* __restrict__ x,
                                             float* __restrict__ rms){
  int p = blockIdx.x * 256 + threadIdx.x;     // 4096
  float acc = 0.f;
  for (int c = 0; c < C_DIM; ++c){
    float v = x[c * P_DIM + p];
    acc = fmaf(v, v, acc);
  }
  rms[p] = rsqrtf(acc * (1.0f / (float)C_DIM) + 1e-6f);
}

// ---------------- K4: xn[c][p] = x[c][p] * s[c] * rms[p]  (c-major, like x) -
__global__ __launch_bounds__(256) void k_xn(const float* __restrict__ x,
                                            const float* __restrict__ s,
                                            const float* __restrict__ rms,
                                            float* __restrict__ xn){
  int idx = blockIdx.x * 256 + threadIdx.x;   // 2097152
  int c = idx >> 12;
  int p = idx & 4095;
  xn[idx] = x[idx] * s[c] * rms[p];
}

// ---------------- K5: qkv[p][j] = sum_c xn[c][p] * qkv_w[c][j] --------------
// block = 256 threads, 8 pixels/block; thread handles 6 cols (stride 256)
__global__ __launch_bounds__(256) void k_gemm_qkv(const float* __restrict__ xn,
                                                  const float* __restrict__ w,
                                                  float* __restrict__ qkv){
  const int tid = threadIdx.x;
  const int p0 = blockIdx.x * 8;
  float acc[6][8];
#pragma unroll
  for (int j = 0; j < 6; ++j)
#pragma unroll
    for (int pp = 0; pp < 8; ++pp) acc[j][pp] = 0.f;

  for (int c = 0; c < C_DIM; ++c){
    const float4 a0 = *reinterpret_cast<const float4*>(xn + c * P_DIM + p0);
    const float4 a1 = *reinterpret_cast<const float4*>(xn + c * P_DIM + p0 + 4);
    float a[8] = { a0.x, a0.y, a0.z, a0.w, a1.x, a1.y, a1.z, a1.w };
    const float* wrow = w + c * 1536;
    float wv[6];
#pragma unroll
    for (int j = 0; j < 6; ++j) wv[j] = wrow[j * 256 + tid];
#pragma unroll
    for (int j = 0; j < 6; ++j)
#pragma unroll
      for (int pp = 0; pp < 8; ++pp)
        acc[j][pp] = fmaf(a[pp], wv[j], acc[j][pp]);
  }
#pragma unroll
  for (int j = 0; j < 6; ++j){
    int col = j * 256 + tid;
#pragma unroll
    for (int pp = 0; pp < 8; ++pp)
      qkv[(p0 + pp) * 1536 + col] = acc[j][pp];
  }
}

// ---------------- K6: per-(p,head,{q,k}): L2-normalize*sqrt(scale), rope ----
// one wave per unit; in-place on qkv
__global__ __launch_bounds__(256) void k_normrope(float* __restrict__ qkv,
                                                  const float* __restrict__ scale,
                                                  const float* __restrict__ cos_t,
                                                  const float* __restrict__ sin_t){
  int u = blockIdx.x * 4 + (threadIdx.x >> 6);   // 65536 units = 4096*8*2
  int d = threadIdx.x & 63;
  int p = u >> 4;
  int r = u & 15;
  int head = r >> 1;
  int qk = r & 1;
  int base = p * 1536 + qk * 512 + head * 64;
  float v = qkv[base + d];
  float ss = wave_sum(v * v);
  v *= sqrtf(scale[head]) * rsqrtf(ss + 1e-6f);
  float partner = __shfl_xor(v, 16, 64);
  int hw = p & 1023;
  int cb = (hw * 8 + head) * 16;
  float outv;
  if (d < 16)       outv = v * cos_t[cb + d]       - partner * sin_t[cb + d];
  else if (d < 32)  outv = v * cos_t[cb + d - 16]  + partner * sin_t[cb + d - 16];
  else              outv = v;
  qkv[base + d] = outv;
}

// ---------------- K7: neighborhood attention, one wave per (pixel, head) ----
__global__ __launch_bounds__(64) void k_attn(const float* __restrict__ qkv,
                                             float* __restrict__ o){
  __shared__ float k_lds[KW * 65];
  __shared__ float v_lds[KW * 65];
  __shared__ float q_lds[64];
  __shared__ float a_lds[64];
  int bid = blockIdx.x;                 // 32768 = 4096*8
  int head = bid & 7;
  int p = bid >> 3;
  int t = p >> 10, h = (p >> 5) & 31, w = p & 31;
  int hs = min(max(h - 3, 0), 25);
  int wss = min(max(w - 3, 0), 25);
  int d = threadIdx.x;

  q_lds[d] = qkv[p * 1536 + head * 64 + d];
  for (int r = 0; r < KW; ++r){
    int nr = hs + r / 7;
    int nc = wss + r % 7;
    int pn = (t << 10) + (nr << 5) + nc;
    k_lds[r * 65 + d] = qkv[pn * 1536 + 512  + head * 64 + d];
    v_lds[r * 65 + d] = qkv[pn * 1536 + 1024 + head * 64 + d];
  }
  __syncthreads();

  float logit = -1e30f;
  if (d < KW){
    float acc = 0.f;
    for (int e = 0; e < 64; ++e)
      acc = fmaf(q_lds[e], k_lds[d * 65 + e], acc);
    logit = acc;
  }
  float m = wave_max(logit);
  float ex = (d < KW) ? expf(logit - m) : 0.f;
  float ssum = wave_sum(ex);
  a_lds[d] = ex / ssum;
  __syncthreads();

  float acc = 0.f;
  for (int r = 0; r < KW; ++r)
    acc = fmaf(a_lds[r], v_lds[r * 65 + d], acc);
  o[p * 512 + head * 64 + d] = acc;
}

// ---------------- K8: y[p][c2] = sum_c o[p][c] * out_w[c][c2] ---------------
__global__ __launch_bounds__(256) void k_gemm_out(const float* __restrict__ o,
                                                  const float* __restrict__ w,
                                                  float* __restrict__ y){
  const int tid = threadIdx.x;
  const int p0 = blockIdx.x * 8;
  float acc[2][8];
#pragma unroll
  for (int b = 0; b < 2; ++b)
#pragma unroll
    for (int pp = 0; pp < 8; ++pp) acc[b][pp] = 0.f;

  for (int c = 0; c < C_DIM; ++c){
    float a[8];
#pragma unroll
    for (int pp = 0; pp < 8; ++pp) a[pp] = o[(p0 + pp) * 512 + c];
    float w0 = w[c * 512 + tid];
    float w1 = w[c * 512 + 256 + tid];
#pragma unroll
    for (int pp = 0; pp < 8; ++pp){
      acc[0][pp] = fmaf(a[pp], w0, acc[0][pp]);
      acc[1][pp] = fmaf(a[pp], w1, acc[1][pp]);
    }
  }
#pragma unroll
  for (int b = 0; b < 2; ++b)
#pragma unroll
    for (int pp = 0; pp < 8; ++pp)
      y[(p0 + pp) * 512 + b * 256 + tid] = acc[b][pp];
}

// ---------------- K9: out[c][p] = y[p][c] + x[c][p]  (transpose via LDS) ----
__global__ __launch_bounds__(256) void k_finish(const float* __restrict__ y,
                                                const float* __restrict__ x,
                                                float* __restrict__ out){
  __shared__ float tile[64 * 65];
  int bp = blockIdx.x & 63;       // pixel tile
  int bc = blockIdx.x >> 6;       // channel tile (8)
  int p0 = bp * 64, c0 = bc * 64;
  int lane = threadIdx.x & 63, grp = threadIdx.x >> 6;
  for (int i = grp; i < 64; i += 4)
    tile[i * 65 + lane] = y[(p0 + i) * 512 + c0 + lane];
  __syncthreads();
  for (int j = grp; j < 64; j += 4){
    int c = c0 + j;
    int p = p0 + lane;
    out[c * P_DIM + p] = tile[lane * 65 + j] + x[c * P_DIM + p];
  }
}

extern "C" void kernel_launch(void* const* d_in, const int* in_sizes, int n_in,
                              void* d_out, int out_size, void* d_ws, size_t ws_size,
                              hipStream_t stream){
  const float* x      = (const float*)d_in[0];
  const float* pos    = (const float*)d_in[1];
  const float* cond   = (const float*)d_in[2];
  const float* norm_w = (const float*)d_in[3];
  const float* qkv_w  = (const float*)d_in[4];
  const float* scale  = (const float*)d_in[5];
  const float* out_w  = (const float*)d_in[6];
  float* out = (float*)d_out;

  char* wp = (char*)d_ws;
  auto alloc = [&](size_t bytes) -> char* {
    char* r = wp;
    wp += (bytes + 255) & ~((size_t)255);
    return r;
  };
  float* s_f   = (float*)alloc(512 * 4);
  float* rms_f = (float*)alloc(4096 * 4);
  float* cos_t = (float*)alloc(131072 * 4);
  float* sin_t = (float*)alloc(131072 * 4);
  float* xn    = (float*)alloc((size_t)2097152 * 4);
  float* qkv   = (float*)alloc((size_t)4096 * 1536 * 4);
  float* o_r   = (float*)alloc((size_t)4096 * 512 * 4);
  float* y_r   = (float*)alloc((size_t)4096 * 512 * 4);

  k_prep_s  <<<1,     512, 0, stream>>>(cond, norm_w, s_f);
  k_tables  <<<512,   256, 0, stream>>>(pos, cos_t, sin_t);
  k_rms     <<<16,    256, 0, stream>>>(x, rms_f);
  k_xn      <<<8192,  256, 0, stream>>>(x, s_f, rms_f, xn);
  k_gemm_qkv<<<512,   256, 0, stream>>>(xn, qkv_w, qkv);
  k_normrope<<<16384, 256, 0, stream>>>(qkv, scale, cos_t, sin_t);
  k_attn    <<<32768,  64, 0, stream>>>(qkv, o_r);
  k_gemm_out<<<512,   256, 0, stream>>>(o_r, out_w, y_r);
  k_finish  <<<512,   256, 0, stream>>>(y_r, x, out);
}

// Round 3
// 213.025 us; speedup vs baseline: 2.5685x; 2.5685x over previous
//
#include <hip/hip_runtime.h>
#include <hip/hip_bf16.h>

typedef __hip_bfloat16 bf16;
#define F32(b) __bfloat162float(b)
#define B16(f) __float2bfloat16(f)

typedef __attribute__((ext_vector_type(8))) short short8;   // MFMA A/B frag (8 bf16)
typedef __attribute__((ext_vector_type(4))) float f32x4;    // MFMA C/D frag

#define C_DIM 512
#define P_DIM 4096   // pixel p = t*1024 + h*32 + w ; x flat index = c*4096 + p

__device__ __forceinline__ float wave_sum(float v){
#pragma unroll
  for (int o = 32; o > 0; o >>= 1) v += __shfl_xor(v, o, 64);
  return v;
}
__device__ __forceinline__ float wave_max(float v){
#pragma unroll
  for (int o = 32; o > 0; o >>= 1) v = fmaxf(v, __shfl_xor(v, o, 64));
  return v;
}
__device__ __forceinline__ float bfu2f(unsigned short u){ return __uint_as_float(((unsigned)u) << 16); }

// ---------------- K1: s[c] = 1 + sum_f cond[f]*norm_w[f][c] ----------------
__global__ __launch_bounds__(512) void k_prep_s(const float* __restrict__ cond,
                                                const float* __restrict__ norm_w,
                                                float* __restrict__ s){
  int c = threadIdx.x;
  float acc = 0.f;
  for (int f = 0; f < 256; ++f)
    acc = fmaf(cond[f], norm_w[f * 512 + c], acc);
  s[c] = acc + 1.0f;
}

// ---------------- K2: rope cos/sin tables, [(hw*8+hd)*16 + j] ---------------
__global__ __launch_bounds__(256) void k_tables(const float* __restrict__ pos,
                                                float* __restrict__ cos_t,
                                                float* __restrict__ sin_t){
  int idx = blockIdx.x * 256 + threadIdx.x;   // 131072 = 1024*8*16
  int j  = idx & 15;
  int hd = (idx >> 4) & 7;
  int hw = idx >> 7;
  int axis = j >> 3;
  int i = j & 7;
  const float LOG_PI = 1.1447298858494002f;
  const float LOG10F = 2.302585092994046f;
  float f = expf(LOG_PI + (float)(i * 8 + hd) * (LOG10F / 64.0f));
  float th = pos[hw * 2 + axis] * f;
  cos_t[idx] = cosf(th);
  sin_t[idx] = sinf(th);
}

// ---------------- K3: rms[p] — 64 blocks, 64 px each ------------------------
__global__ __launch_bounds__(256) void k_rms(const float* __restrict__ x,
                                             float* __restrict__ rms){
  __shared__ float red[4][64];
  int p0 = blockIdx.x * 64;
  int co = threadIdx.x >> 6, pl = threadIdx.x & 63;
  float acc = 0.f;
  for (int c = co; c < 512; c += 4){
    float v = x[c * P_DIM + p0 + pl];
    acc = fmaf(v, v, acc);
  }
  red[co][pl] = acc;
  __syncthreads();
  if (threadIdx.x < 64){
    int p = threadIdx.x;
    float ss = red[0][p] + red[1][p] + red[2][p] + red[3][p];
    rms[p0 + p] = rsqrtf(ss * (1.0f / 512.0f) + 1e-6f);
  }
}

// ---------------- K4: cast+transpose weights to [n][k] bf16 -----------------
__global__ __launch_bounds__(256) void k_castwT(const float* __restrict__ qkv_w,
                                                const float* __restrict__ out_w,
                                                bf16* __restrict__ qkvT,
                                                bf16* __restrict__ outT){
  __shared__ float tile[64][65];
  int bid = blockIdx.x;          // 0..191 qkv_w (24 n-tiles x 8 c-tiles), 192..255 out_w
  const float* src; bf16* dst; int NW, n0, c0;
  if (bid < 192){ src = qkv_w; dst = qkvT; NW = 1536; n0 = (bid % 24) * 64; c0 = (bid / 24) * 64; }
  else { int b = bid - 192; src = out_w; dst = outT; NW = 512; n0 = (b & 7) * 64; c0 = (b >> 3) * 64; }
  int grp = threadIdx.x >> 6, lane = threadIdx.x & 63;
  for (int i = grp; i < 64; i += 4)
    tile[i][lane] = src[(c0 + i) * NW + n0 + lane];
  __syncthreads();
  for (int j = grp; j < 64; j += 4)
    dst[(n0 + j) * 512 + c0 + lane] = B16(tile[lane][j]);
}

// ---------------- K5: xn bf16 [p][c] = x[c][p]*s[c]*rms[p] (transpose) ------
__global__ __launch_bounds__(256) void k_xnt(const float* __restrict__ x,
                                             const float* __restrict__ s,
                                             const float* __restrict__ rms,
                                             bf16* __restrict__ xn){
  __shared__ float tile[64][65];
  int bp = blockIdx.x & 63, bc = blockIdx.x >> 6;
  int p0 = bp * 64, c0 = bc * 64;
  int grp = threadIdx.x >> 6, lane = threadIdx.x & 63;
  for (int i = grp; i < 64; i += 4)
    tile[i][lane] = x[(c0 + i) * P_DIM + p0 + lane] * s[c0 + i];
  __syncthreads();
  for (int j = grp; j < 64; j += 4){
    float rv = rms[p0 + j];
    xn[(size_t)(p0 + j) * 512 + c0 + lane] = B16(tile[lane][j] * rv);
  }
}

// ---------------- K6: MFMA GEMM  C[m][n] = sum_k A[m][k]*BT[n][k] -----------
// A: [4096][512] bf16 ; BT: [NW][512] bf16 ; tile 64x64, BK=32, 4 waves
// mode 0: qkv gemm — n<1024 -> tmp_qk fp32 [m][1024]; n>=1024 -> qkv_bf bf16 [m][1536]
// mode 2: out gemm — y fp32 [m][512]
__global__ __launch_bounds__(256) void k_gemm(const bf16* __restrict__ Ab,
                                              const bf16* __restrict__ BTb,
                                              float* __restrict__ outF,
                                              bf16* __restrict__ outB,
                                              int mode){
  __shared__ unsigned short a_t[64 * 40];   // padded stride 40 shorts (80B, 16B-aligned)
  __shared__ unsigned short b_t[64 * 40];
  const unsigned short* A  = (const unsigned short*)Ab;
  const unsigned short* BT = (const unsigned short*)BTb;
  int m0 = blockIdx.x * 64;
  int n0 = blockIdx.y * 64;
  int tid = threadIdx.x;
  int w = tid >> 6, l = tid & 63;
  int rsel = tid >> 2, seg = tid & 3;       // staging row / 16B segment

  f32x4 acc[4];
#pragma unroll
  for (int j = 0; j < 4; ++j)
#pragma unroll
    for (int r = 0; r < 4; ++r) acc[j][r] = 0.f;

  int lrow = w * 16 + (l & 15);
  int quad = l >> 4;

  for (int kk = 0; kk < 512; kk += 32){
    *(uint4*)&a_t[rsel * 40 + seg * 8] = *(const uint4*)&A[(size_t)(m0 + rsel) * 512 + kk + seg * 8];
    *(uint4*)&b_t[rsel * 40 + seg * 8] = *(const uint4*)&BT[(size_t)(n0 + rsel) * 512 + kk + seg * 8];
    __syncthreads();
    short8 af = *(const short8*)&a_t[lrow * 40 + quad * 8];
#pragma unroll
    for (int j = 0; j < 4; ++j){
      short8 bfr = *(const short8*)&b_t[(j * 16 + (l & 15)) * 40 + quad * 8];
      acc[j] = __builtin_amdgcn_mfma_f32_16x16x32_bf16(af, bfr, acc[j], 0, 0, 0);
    }
    __syncthreads();
  }
  // epilogue: D col = lane&15, row = (lane>>4)*4 + reg
  int cb = l & 15;
#pragma unroll
  for (int j = 0; j < 4; ++j){
    int col = n0 + j * 16 + cb;
#pragma unroll
    for (int r = 0; r < 4; ++r){
      int rowg = m0 + w * 16 + (l >> 4) * 4 + r;
      float v = acc[j][r];
      if (mode == 0){
        if (n0 < 1024) outF[(size_t)rowg * 1024 + col] = v;
        else           outB[(size_t)rowg * 1536 + col] = B16(v);
      } else {
        outF[(size_t)rowg * 512 + col] = v;
      }
    }
  }
}

// ---------------- K7: q/k L2-norm*sqrt(scale) + rope ; fp32 in, bf16 out ----
__global__ __launch_bounds__(256) void k_normrope(const float* __restrict__ tmp_qk,
                                                  const float* __restrict__ scale,
                                                  const float* __restrict__ cos_t,
                                                  const float* __restrict__ sin_t,
                                                  bf16* __restrict__ qkv_bf){
  int u = blockIdx.x * 4 + (threadIdx.x >> 6);   // 65536 = 4096*8*2
  int d = threadIdx.x & 63;
  int p = u >> 4;
  int r = u & 15;
  int head = r >> 1;
  int qk = r & 1;
  float v = tmp_qk[(size_t)p * 1024 + qk * 512 + head * 64 + d];
  float ss = wave_sum(v * v);
  v *= sqrtf(scale[head]) * rsqrtf(ss + 1e-6f);
  float partner = __shfl_xor(v, 16, 64);
  int cb = ((p & 1023) * 8 + head) * 16;
  float outv;
  if (d < 16)       outv = v * cos_t[cb + d]      - partner * sin_t[cb + d];
  else if (d < 32)  outv = v * cos_t[cb + d - 16] + partner * sin_t[cb + d - 16];
  else              outv = v;
  qkv_bf[(size_t)p * 1536 + qk * 512 + head * 64 + d] = B16(outv);
}

// ---------------- K8: patch attention — block = (8x8 patch, head) -----------
// K/V window union = 14x14 px, bf16 in LDS; K transposed for QK phase.
#define KT_S 198   // kT row stride (shorts)
#define V_S  66    // v row stride (shorts)
__global__ __launch_bounds__(256) void k_attn(const bf16* __restrict__ qkv_bfp,
                                              bf16* __restrict__ o_bf){
  __shared__ unsigned short kT[64 * KT_S];   // [ch][px]
  __shared__ unsigned short vL[196 * V_S];   // [px][ch]
  __shared__ float qf[4][64];
  __shared__ float af[4][64];
  const unsigned short* qkv = (const unsigned short*)qkv_bfp;

  int bid = blockIdx.x;            // 512 = 64 patches * 8 heads
  int head = bid & 7;
  int patch = bid >> 3;
  int t = patch >> 4;
  int ph = (patch >> 2) & 3, pw = patch & 3;
  int h0 = ph * 8, w0 = pw * 8;
  int rs = min(max(h0 - 3, 0), 18);
  int cs = min(max(w0 - 3, 0), 18);
  int tbase = t << 10;
  int tid = threadIdx.x;

  // stage K (transposed) and V
  for (int idx = tid; idx < 196 * 32; idx += 256){
    int px = idx >> 5, cp = idx & 31;
    int rr = px / 14, cc = px - rr * 14;
    size_t pn = (size_t)(tbase + (rs + rr) * 32 + (cs + cc));
    unsigned ku = *(const unsigned*)&qkv[pn * 1536 + 512  + head * 64 + cp * 2];
    unsigned vu = *(const unsigned*)&qkv[pn * 1536 + 1024 + head * 64 + cp * 2];
    kT[(2 * cp)     * KT_S + px] = (unsigned short)(ku & 0xffffu);
    kT[(2 * cp + 1) * KT_S + px] = (unsigned short)(ku >> 16);
    *(unsigned*)&vL[px * V_S + 2 * cp] = vu;
  }
  __syncthreads();

  int w = tid >> 6, lane = tid & 63;
  int r7 = lane / 7, c7 = lane - r7 * 7;

  for (int qi = 0; qi < 16; ++qi){
    int q_l = w * 16 + qi;
    int qh = q_l >> 3, qw = q_l & 7;
    int hq = h0 + qh, wq = w0 + qw;
    int p = tbase + hq * 32 + wq;
    qf[w][lane] = bfu2f(qkv[(size_t)p * 1536 + head * 64 + lane]);
    int wr0 = min(max(hq - 3, 0), 25) - rs;
    int wc0 = min(max(wq - 3, 0), 25) - cs;
    int pxl = (wr0 + r7) * 14 + wc0 + c7;
    pxl = min(pxl, 195);
    float acc = 0.f;
#pragma unroll
    for (int e = 0; e < 64; ++e)
      acc = fmaf(qf[w][e], bfu2f(kT[e * KT_S + pxl]), acc);
    float logit = (lane < 49) ? acc : -1e30f;
    float mx = wave_max(logit);
    float ex = (lane < 49) ? __expf(logit - mx) : 0.f;
    float sm = wave_sum(ex);
    af[w][lane] = ex / sm;
    float out = 0.f;
#pragma unroll
    for (int rr = 0; rr < 7; ++rr){
      int pb = (wr0 + rr) * 14 + wc0;
#pragma unroll
      for (int cc = 0; cc < 7; ++cc)
        out = fmaf(af[w][rr * 7 + cc], bfu2f(vL[(pb + cc) * V_S + lane]), out);
    }
    o_bf[(size_t)p * 512 + head * 64 + lane] = B16(out);
  }
}

// ---------------- K9: out[c][p] = y[p][c] + x[c][p] -------------------------
__global__ __launch_bounds__(256) void k_finish(const float* __restrict__ y,
                                                const float* __restrict__ x,
                                                float* __restrict__ out){
  __shared__ float tile[64 * 65];
  int bp = blockIdx.x & 63;
  int bc = blockIdx.x >> 6;
  int p0 = bp * 64, c0 = bc * 64;
  int lane = threadIdx.x & 63, grp = threadIdx.x >> 6;
  for (int i = grp; i < 64; i += 4)
    tile[i * 65 + lane] = y[(size_t)(p0 + i) * 512 + c0 + lane];
  __syncthreads();
  for (int j = grp; j < 64; j += 4){
    int c = c0 + j;
    int p = p0 + lane;
    out[(size_t)c * P_DIM + p] = tile[lane * 65 + j] + x[(size_t)c * P_DIM + p];
  }
}

extern "C" void kernel_launch(void* const* d_in, const int* in_sizes, int n_in,
                              void* d_out, int out_size, void* d_ws, size_t ws_size,
                              hipStream_t stream){
  const float* x      = (const float*)d_in[0];
  const float* pos    = (const float*)d_in[1];
  const float* cond   = (const float*)d_in[2];
  const float* norm_w = (const float*)d_in[3];
  const float* qkv_w  = (const float*)d_in[4];
  const float* scale  = (const float*)d_in[5];
  const float* out_w  = (const float*)d_in[6];
  float* out = (float*)d_out;

  char* wp = (char*)d_ws;
  auto alloc = [&](size_t bytes) -> char* {
    char* r = wp;
    wp += (bytes + 255) & ~((size_t)255);
    return r;
  };
  float* s_f    = (float*)alloc(512 * 4);
  float* rms_f  = (float*)alloc(4096 * 4);
  float* cos_t  = (float*)alloc(131072 * 4);
  float* sin_t  = (float*)alloc(131072 * 4);
  bf16*  xn     = (bf16*) alloc((size_t)4096 * 512 * 2);
  bf16*  qkvT   = (bf16*) alloc((size_t)1536 * 512 * 2);
  bf16*  outT   = (bf16*) alloc((size_t)512 * 512 * 2);
  float* tmp_qk = (float*)alloc((size_t)4096 * 1024 * 4);
  bf16*  qkv_bf = (bf16*) alloc((size_t)4096 * 1536 * 2);
  bf16*  o_bf   = (bf16*) alloc((size_t)4096 * 512 * 2);
  float* y_f    = (float*)alloc((size_t)4096 * 512 * 4);

  k_prep_s  <<<1,           512, 0, stream>>>(cond, norm_w, s_f);
  k_tables  <<<512,         256, 0, stream>>>(pos, cos_t, sin_t);
  k_rms     <<<64,          256, 0, stream>>>(x, rms_f);
  k_castwT  <<<256,         256, 0, stream>>>(qkv_w, out_w, qkvT, outT);
  k_xnt     <<<512,         256, 0, stream>>>(x, s_f, rms_f, xn);
  k_gemm    <<<dim3(64,24), 256, 0, stream>>>(xn, qkvT, tmp_qk, qkv_bf, 0);
  k_normrope<<<16384,       256, 0, stream>>>(tmp_qk, scale, cos_t, sin_t, qkv_bf);
  k_attn    <<<512,         256, 0, stream>>>(qkv_bf, o_bf);
  k_gemm    <<<dim3(64,8),  256, 0, stream>>>(o_bf, outT, y_f, nullptr, 2);
  k_finish  <<<512,         256, 0, stream>>>(y_f, x, out);
}

// Round 4
// 158.660 us; speedup vs baseline: 3.4486x; 1.3426x over previous
//
#include <hip/hip_runtime.h>
#include <hip/hip_bf16.h>

typedef __hip_bfloat16 bf16;
#define F32(b) __bfloat162float(b)
#define B16(f) __float2bfloat16(f)

typedef __attribute__((ext_vector_type(8))) short short8;   // MFMA A/B frag (8 bf16)
typedef __attribute__((ext_vector_type(4))) float f32x4;    // MFMA C/D frag

#define C_DIM 512
#define P_DIM 4096   // pixel p = t*1024 + h*32 + w ; x flat index = c*4096 + p

__device__ __forceinline__ float wave_sum(float v){
#pragma unroll
  for (int o = 32; o > 0; o >>= 1) v += __shfl_xor(v, o, 64);
  return v;
}

// ---------------- K1: s[c] = 1 + sum_f cond[f]*norm_w[f][c] ----------------
__global__ __launch_bounds__(256) void k_prep_s(const float* __restrict__ cond,
                                                const float* __restrict__ norm_w,
                                                float* __restrict__ s){
  __shared__ float red[8][33];
  int c_l = threadIdx.x & 31, fo = threadIdx.x >> 5;
  int c = blockIdx.x * 32 + c_l;
  float acc = 0.f;
  for (int f = fo * 32; f < fo * 32 + 32; ++f)
    acc = fmaf(cond[f], norm_w[f * 512 + c], acc);
  red[fo][c_l] = acc;
  __syncthreads();
  if (threadIdx.x < 32){
    float a = 0.f;
#pragma unroll
    for (int i = 0; i < 8; ++i) a += red[i][c_l];
    s[blockIdx.x * 32 + c_l] = a + 1.0f;
  }
}

// ---------------- K2: rope cos/sin tables, [(hw*8+hd)*16 + j] ---------------
__global__ __launch_bounds__(256) void k_tables(const float* __restrict__ pos,
                                                float* __restrict__ cos_t,
                                                float* __restrict__ sin_t){
  int idx = blockIdx.x * 256 + threadIdx.x;   // 131072 = 1024*8*16
  int j  = idx & 15;
  int hd = (idx >> 4) & 7;
  int hw = idx >> 7;
  int axis = j >> 3;
  int i = j & 7;
  const float LOG_PI = 1.1447298858494002f;
  const float LOG10F = 2.302585092994046f;
  float f = expf(LOG_PI + (float)(i * 8 + hd) * (LOG10F / 64.0f));
  float th = pos[hw * 2 + axis] * f;
  cos_t[idx] = cosf(th);
  sin_t[idx] = sinf(th);
}

// ---------------- K3: partial sum-of-squares per pixel (atomic) -------------
// 512 blocks = 64 p-tiles x 8 c-slices ; rms_ss must be zeroed first
__global__ __launch_bounds__(256) void k_rms(const float* __restrict__ x,
                                             float* __restrict__ rms_ss){
  __shared__ float red[4][64];
  int bp = blockIdx.x & 63, bc = blockIdx.x >> 6;
  int co = threadIdx.x >> 6, pl = threadIdx.x & 63;
  int p = bp * 64 + pl;
  float acc = 0.f;
  for (int c = bc * 64 + co; c < bc * 64 + 64; c += 4){
    float v = x[c * P_DIM + p];
    acc = fmaf(v, v, acc);
  }
  red[co][pl] = acc;
  __syncthreads();
  if (threadIdx.x < 64){
    int q = threadIdx.x;
    float ss = red[0][q] + red[1][q] + red[2][q] + red[3][q];
    atomicAdd(&rms_ss[bp * 64 + q], ss);
  }
}

// ---------------- K4: cast+transpose weights to [n][k] bf16 -----------------
__global__ __launch_bounds__(256) void k_castwT(const float* __restrict__ qkv_w,
                                                const float* __restrict__ out_w,
                                                bf16* __restrict__ qkvT,
                                                bf16* __restrict__ outT){
  __shared__ float tile[64][65];
  int bid = blockIdx.x;          // 0..191 qkv_w, 192..255 out_w
  const float* src; bf16* dst; int NW, n0, c0;
  if (bid < 192){ src = qkv_w; dst = qkvT; NW = 1536; n0 = (bid % 24) * 64; c0 = (bid / 24) * 64; }
  else { int b = bid - 192; src = out_w; dst = outT; NW = 512; n0 = (b & 7) * 64; c0 = (b >> 3) * 64; }
  int grp = threadIdx.x >> 6, lane = threadIdx.x & 63;
  for (int i = grp; i < 64; i += 4)
    tile[i][lane] = src[(c0 + i) * NW + n0 + lane];
  __syncthreads();
  for (int j = grp; j < 64; j += 4)
    dst[(n0 + j) * 512 + c0 + lane] = B16(tile[lane][j]);
}

// ---------------- K5: xn bf16 [p][c] = x[c][p]*s[c]*rsqrt(ss/512+eps) -------
__global__ __launch_bounds__(256) void k_xnt(const float* __restrict__ x,
                                             const float* __restrict__ s,
                                             const float* __restrict__ rms_ss,
                                             bf16* __restrict__ xn){
  __shared__ float tile[64][65];
  int bp = blockIdx.x & 63, bc = blockIdx.x >> 6;
  int p0 = bp * 64, c0 = bc * 64;
  int grp = threadIdx.x >> 6, lane = threadIdx.x & 63;
  for (int i = grp; i < 64; i += 4)
    tile[i][lane] = x[(c0 + i) * P_DIM + p0 + lane] * s[c0 + i];
  __syncthreads();
  for (int j = grp; j < 64; j += 4){
    float rv = rsqrtf(rms_ss[p0 + j] * (1.0f / 512.0f) + 1e-6f);
    xn[(size_t)(p0 + j) * 512 + c0 + lane] = B16(tile[lane][j] * rv);
  }
}

// ---------------- K6: MFMA GEMM qkv: [4096][512] @ T[1536][512] -> bf16 -----
__global__ __launch_bounds__(256) void k_gemm_qkv(const bf16* __restrict__ Ab,
                                                  const bf16* __restrict__ BTb,
                                                  bf16* __restrict__ qkv_bf){
  __shared__ unsigned short a_t[64 * 40];
  __shared__ unsigned short b_t[64 * 40];
  const unsigned short* A  = (const unsigned short*)Ab;
  const unsigned short* BT = (const unsigned short*)BTb;
  int m0 = blockIdx.x * 64;
  int n0 = blockIdx.y * 64;
  int tid = threadIdx.x;
  int w = tid >> 6, l = tid & 63;
  int rsel = tid >> 2, seg = tid & 3;

  f32x4 acc[4];
#pragma unroll
  for (int j = 0; j < 4; ++j)
#pragma unroll
    for (int r = 0; r < 4; ++r) acc[j][r] = 0.f;

  int lrow = w * 16 + (l & 15);
  int quad = l >> 4;

  for (int kk = 0; kk < 512; kk += 32){
    *(uint4*)&a_t[rsel * 40 + seg * 8] = *(const uint4*)&A[(size_t)(m0 + rsel) * 512 + kk + seg * 8];
    *(uint4*)&b_t[rsel * 40 + seg * 8] = *(const uint4*)&BT[(size_t)(n0 + rsel) * 512 + kk + seg * 8];
    __syncthreads();
    short8 af = *(const short8*)&a_t[lrow * 40 + quad * 8];
#pragma unroll
    for (int j = 0; j < 4; ++j){
      short8 bfr = *(const short8*)&b_t[(j * 16 + (l & 15)) * 40 + quad * 8];
      acc[j] = __builtin_amdgcn_mfma_f32_16x16x32_bf16(af, bfr, acc[j], 0, 0, 0);
    }
    __syncthreads();
  }
  int cb = l & 15;
#pragma unroll
  for (int j = 0; j < 4; ++j){
    int col = n0 + j * 16 + cb;
#pragma unroll
    for (int r = 0; r < 4; ++r){
      int rowg = m0 + w * 16 + (l >> 4) * 4 + r;
      qkv_bf[(size_t)rowg * 1536 + col] = B16(acc[j][r]);
    }
  }
}

// ---------------- K7: q/k L2-norm*sqrt(scale) + rope, bf16 in-place ---------
__global__ __launch_bounds__(256) void k_normrope(bf16* __restrict__ qkv_bf,
                                                  const float* __restrict__ scale,
                                                  const float* __restrict__ cos_t,
                                                  const float* __restrict__ sin_t){
  int u = blockIdx.x * 4 + (threadIdx.x >> 6);   // 65536 = 4096*8*2
  int d = threadIdx.x & 63;
  int p = u >> 4;
  int r = u & 15;
  int head = r >> 1;
  int qk = r & 1;
  size_t base = (size_t)p * 1536 + qk * 512 + head * 64;
  float v = F32(qkv_bf[base + d]);
  float ss = wave_sum(v * v);
  v *= sqrtf(scale[head]) * rsqrtf(ss + 1e-6f);
  float partner = __shfl_xor(v, 16, 64);
  int cb = ((p & 1023) * 8 + head) * 16;
  float outv;
  if (d < 16)       outv = v * cos_t[cb + d]      - partner * sin_t[cb + d];
  else if (d < 32)  outv = v * cos_t[cb + d - 16] + partner * sin_t[cb + d - 16];
  else              outv = v;
  qkv_bf[base + d] = B16(outv);
}

// ---------------- K8: MFMA neighborhood attention ---------------------------
// block = (8x8 patch, head); union window 14x14 = 196 keys (pad to 208 QK / 224 PV)
// kp region: K [208][80] shorts, then reused as P [64][232]
// vT: V transposed [64 ch][232] shorts
#define KL_S 80
#define VT_S 232
#define PP_S 232
__global__ __launch_bounds__(256) void k_attn(const bf16* __restrict__ qkv_bfp,
                                              bf16* __restrict__ o_bf){
  __shared__ unsigned short kp[208 * KL_S];     // 33280 B (>= P 64*232=29696 B)
  __shared__ unsigned short vT[64 * VT_S];      // 29696 B
  const unsigned short* qkv = (const unsigned short*)qkv_bfp;

  int bid = blockIdx.x;            // 512 = 64 patches * 8 heads
  int head = bid & 7;
  int patch = bid >> 3;
  int t = patch >> 4;
  int ph = (patch >> 2) & 3, pw = patch & 3;
  int h0 = ph * 8, w0 = pw * 8;
  int rs = min(max(h0 - 3, 0), 18);
  int cs = min(max(w0 - 3, 0), 18);
  int tbase = t << 10;
  int tid = threadIdx.x;
  int cp = tid & 31, pxg = tid >> 5;

  // stage K [px][ch], px 0..207 (>=196 zero)
  for (int i = 0; i < 26; ++i){
    int px = i * 8 + pxg;
    unsigned val = 0;
    if (px < 196){
      int rr = px / 14, cc = px - rr * 14;
      size_t pn = (size_t)(tbase + (rs + rr) * 32 + (cs + cc));
      val = *(const unsigned*)&qkv[pn * 1536 + 512 + head * 64 + cp * 2];
    }
    *(unsigned*)&kp[px * KL_S + cp * 2] = val;
  }
  // stage V^T [ch][px], px 0..223 (>=196 zero)
  for (int i = 0; i < 14; ++i){
    int pp = i * 8 + pxg;          // px pair
    int px0 = 2 * pp, px1 = px0 + 1;
    unsigned v0 = 0, v1 = 0;
    if (px0 < 196){
      int rr = px0 / 14, cc = px0 - rr * 14;
      size_t pn = (size_t)(tbase + (rs + rr) * 32 + (cs + cc));
      v0 = *(const unsigned*)&qkv[pn * 1536 + 1024 + head * 64 + cp * 2];
    }
    if (px1 < 196){
      int rr = px1 / 14, cc = px1 - rr * 14;
      size_t pn = (size_t)(tbase + (rs + rr) * 32 + (cs + cc));
      v1 = *(const unsigned*)&qkv[pn * 1536 + 1024 + head * 64 + cp * 2];
    }
    unsigned lo = (v0 & 0xffffu) | (v1 << 16);
    unsigned hi = (v0 >> 16) | (v1 & 0xffff0000u);
    *(unsigned*)&vT[(2 * cp) * VT_S + 2 * pp] = lo;
    *(unsigned*)&vT[(2 * cp + 1) * VT_S + 2 * pp] = hi;
  }

  int w = tid >> 6, l = tid & 63;
  int g = l >> 4, cb = l & 15;

  // Q A-frags straight from global: A[m=cb][k=g*8+j]
  int q_a = w * 16 + cb;
  size_t abase = (size_t)(tbase + (h0 + (q_a >> 3)) * 32 + (w0 + (q_a & 7))) * 1536 + head * 64;
  short8 qa0 = *(const short8*)&qkv[abase + g * 8];
  short8 qa1 = *(const short8*)&qkv[abase + 32 + g * 8];

  __syncthreads();

  // QK^T: 13 n-tiles of 16 keys, K=64 (2 chunks)
  f32x4 acc[13];
#pragma unroll
  for (int nt = 0; nt < 13; ++nt)
#pragma unroll
    for (int r = 0; r < 4; ++r) acc[nt][r] = 0.f;
#pragma unroll
  for (int nt = 0; nt < 13; ++nt){
    short8 kb0 = *(const short8*)&kp[(nt * 16 + cb) * KL_S + g * 8];
    short8 kb1 = *(const short8*)&kp[(nt * 16 + cb) * KL_S + 32 + g * 8];
    acc[nt] = __builtin_amdgcn_mfma_f32_16x16x32_bf16(qa0, kb0, acc[nt], 0, 0, 0);
    acc[nt] = __builtin_amdgcn_mfma_f32_16x16x32_bf16(qa1, kb1, acc[nt], 0, 0, 0);
  }
  __syncthreads();   // all waves done reading K before P overwrites kp

  // mask + softmax (rows live on 16-lane groups; row = g*4+r, col = nt*16+cb)
  int wr0[4], wc0[4];
#pragma unroll
  for (int r = 0; r < 4; ++r){
    int q_l = w * 16 + g * 4 + r;
    int hq = h0 + (q_l >> 3), wq = w0 + (q_l & 7);
    wr0[r] = min(max(hq - 3, 0), 25) - rs;
    wc0[r] = min(max(wq - 3, 0), 25) - cs;
  }
  float mx[4] = {-1e30f, -1e30f, -1e30f, -1e30f};
#pragma unroll
  for (int nt = 0; nt < 13; ++nt){
    int kg = nt * 16 + cb;
    int kr = kg / 14, kc = kg - kr * 14;
    bool kvalid = kg < 196;
#pragma unroll
    for (int r = 0; r < 4; ++r){
      bool v = kvalid && ((unsigned)(kr - wr0[r]) < 7u) && ((unsigned)(kc - wc0[r]) < 7u);
      float lg = v ? acc[nt][r] : -1e30f;
      acc[nt][r] = lg;
      mx[r] = fmaxf(mx[r], lg);
    }
  }
#pragma unroll
  for (int off = 1; off < 16; off <<= 1)
#pragma unroll
    for (int r = 0; r < 4; ++r) mx[r] = fmaxf(mx[r], __shfl_xor(mx[r], off, 64));
  float sm[4] = {0.f, 0.f, 0.f, 0.f};
#pragma unroll
  for (int nt = 0; nt < 13; ++nt)
#pragma unroll
    for (int r = 0; r < 4; ++r){
      float e = __expf(acc[nt][r] - mx[r]);
      acc[nt][r] = e;
      sm[r] += e;
    }
#pragma unroll
  for (int off = 1; off < 16; off <<= 1)
#pragma unroll
    for (int r = 0; r < 4; ++r) sm[r] += __shfl_xor(sm[r], off, 64);
  float inv[4];
#pragma unroll
  for (int r = 0; r < 4; ++r) inv[r] = 1.0f / sm[r];

  // write P (bf16) into kp region, layout [q 0..63][232], cols 208..223 zeroed
#pragma unroll
  for (int nt = 0; nt < 13; ++nt)
#pragma unroll
    for (int r = 0; r < 4; ++r)
      *reinterpret_cast<bf16*>(&kp[(w * 16 + g * 4 + r) * PP_S + nt * 16 + cb]) = B16(acc[nt][r] * inv[r]);
#pragma unroll
  for (int r = 0; r < 4; ++r)
    kp[(w * 16 + g * 4 + r) * PP_S + 208 + cb] = 0;
  __syncthreads();

  // PV: out[16q][64ch] = P[16q][224] @ V[224][64ch]
  f32x4 acc2[4];
#pragma unroll
  for (int ct = 0; ct < 4; ++ct)
#pragma unroll
    for (int r = 0; r < 4; ++r) acc2[ct][r] = 0.f;
#pragma unroll
  for (int kt = 0; kt < 7; ++kt){
    short8 pa = *(const short8*)&kp[(w * 16 + cb) * PP_S + kt * 32 + g * 8];
#pragma unroll
    for (int ct = 0; ct < 4; ++ct){
      short8 vb = *(const short8*)&vT[(ct * 16 + cb) * VT_S + kt * 32 + g * 8];
      acc2[ct] = __builtin_amdgcn_mfma_f32_16x16x32_bf16(pa, vb, acc2[ct], 0, 0, 0);
    }
  }
  // D layout: row=(l>>4)*4+r (query), col=ct*16+cb (ch)
#pragma unroll
  for (int ct = 0; ct < 4; ++ct)
#pragma unroll
    for (int r = 0; r < 4; ++r){
      int q_l = w * 16 + g * 4 + r;
      int p = tbase + (h0 + (q_l >> 3)) * 32 + (w0 + (q_l & 7));
      o_bf[(size_t)p * 512 + head * 64 + ct * 16 + cb] = B16(acc2[ct][r]);
    }
}

// ---------------- K9: MFMA GEMM out + fused residual/transpose store --------
__global__ __launch_bounds__(256) void k_gemm_out(const bf16* __restrict__ Ab,
                                                  const bf16* __restrict__ BTb,
                                                  const float* __restrict__ xres,
                                                  float* __restrict__ out){
  __shared__ unsigned short a_t[64 * 40];
  __shared__ unsigned short b_t[64 * 40];
  __shared__ float tile[64][65];
  const unsigned short* A  = (const unsigned short*)Ab;
  const unsigned short* BT = (const unsigned short*)BTb;
  int m0 = blockIdx.x * 64;   // pixels
  int n0 = blockIdx.y * 64;   // channels
  int tid = threadIdx.x;
  int w = tid >> 6, l = tid & 63;
  int rsel = tid >> 2, seg = tid & 3;

  f32x4 acc[4];
#pragma unroll
  for (int j = 0; j < 4; ++j)
#pragma unroll
    for (int r = 0; r < 4; ++r) acc[j][r] = 0.f;

  int lrow = w * 16 + (l & 15);
  int quad = l >> 4;

  for (int kk = 0; kk < 512; kk += 32){
    *(uint4*)&a_t[rsel * 40 + seg * 8] = *(const uint4*)&A[(size_t)(m0 + rsel) * 512 + kk + seg * 8];
    *(uint4*)&b_t[rsel * 40 + seg * 8] = *(const uint4*)&BT[(size_t)(n0 + rsel) * 512 + kk + seg * 8];
    __syncthreads();
    short8 af = *(const short8*)&a_t[lrow * 40 + quad * 8];
#pragma unroll
    for (int j = 0; j < 4; ++j){
      short8 bfr = *(const short8*)&b_t[(j * 16 + (l & 15)) * 40 + quad * 8];
      acc[j] = __builtin_amdgcn_mfma_f32_16x16x32_bf16(af, bfr, acc[j], 0, 0, 0);
    }
    __syncthreads();
  }
  int cb = l & 15;
#pragma unroll
  for (int j = 0; j < 4; ++j)
#pragma unroll
    for (int r = 0; r < 4; ++r)
      tile[w * 16 + (l >> 4) * 4 + r][j * 16 + cb] = acc[j][r];
  __syncthreads();
  int grp = tid >> 6, lane = tid & 63;
  for (int j2 = grp; j2 < 64; j2 += 4){
    int c = n0 + j2;
    int p = m0 + lane;
    out[(size_t)c * P_DIM + p] = tile[lane][j2] + xres[(size_t)c * P_DIM + p];
  }
}

extern "C" void kernel_launch(void* const* d_in, const int* in_sizes, int n_in,
                              void* d_out, int out_size, void* d_ws, size_t ws_size,
                              hipStream_t stream){
  const float* x      = (const float*)d_in[0];
  const float* pos    = (const float*)d_in[1];
  const float* cond   = (const float*)d_in[2];
  const float* norm_w = (const float*)d_in[3];
  const float* qkv_w  = (const float*)d_in[4];
  const float* scale  = (const float*)d_in[5];
  const float* out_w  = (const float*)d_in[6];
  float* out = (float*)d_out;

  char* wp = (char*)d_ws;
  auto alloc = [&](size_t bytes) -> char* {
    char* r = wp;
    wp += (bytes + 255) & ~((size_t)255);
    return r;
  };
  float* s_f    = (float*)alloc(512 * 4);
  float* rms_ss = (float*)alloc(4096 * 4);
  float* cos_t  = (float*)alloc(131072 * 4);
  float* sin_t  = (float*)alloc(131072 * 4);
  bf16*  xn     = (bf16*) alloc((size_t)4096 * 512 * 2);
  bf16*  qkvT   = (bf16*) alloc((size_t)1536 * 512 * 2);
  bf16*  outT   = (bf16*) alloc((size_t)512 * 512 * 2);
  bf16*  qkv_bf = (bf16*) alloc((size_t)4096 * 1536 * 2);
  bf16*  o_bf   = (bf16*) alloc((size_t)4096 * 512 * 2);

  hipMemsetAsync(rms_ss, 0, 4096 * 4, stream);
  k_prep_s  <<<16,          256, 0, stream>>>(cond, norm_w, s_f);
  k_tables  <<<512,         256, 0, stream>>>(pos, cos_t, sin_t);
  k_rms     <<<512,         256, 0, stream>>>(x, rms_ss);
  k_castwT  <<<256,         256, 0, stream>>>(qkv_w, out_w, qkvT, outT);
  k_xnt     <<<512,         256, 0, stream>>>(x, s_f, rms_ss, xn);
  k_gemm_qkv<<<dim3(64,24), 256, 0, stream>>>(xn, qkvT, qkv_bf);
  k_normrope<<<16384,       256, 0, stream>>>(qkv_bf, scale, cos_t, sin_t);
  k_attn    <<<512,         256, 0, stream>>>(qkv_bf, o_bf);
  k_gemm_out<<<dim3(64,8),  256, 0, stream>>>(o_bf, outT, x, out);
}

// Round 5
// 155.114 us; speedup vs baseline: 3.5275x; 1.0229x over previous
//
#include <hip/hip_runtime.h>
#include <hip/hip_bf16.h>

typedef __hip_bfloat16 bf16;
#define F32(b) __bfloat162float(b)
#define B16(f) __float2bfloat16(f)

typedef __attribute__((ext_vector_type(8))) short short8;   // MFMA A/B frag (8 bf16)
typedef __attribute__((ext_vector_type(4))) float f32x4;    // MFMA C/D frag

#define C_DIM 512
#define P_DIM 4096   // pixel p = t*1024 + h*32 + w ; x flat index = c*4096 + p

__device__ __forceinline__ float wave_sum(float v){
#pragma unroll
  for (int o = 32; o > 0; o >>= 1) v += __shfl_xor(v, o, 64);
  return v;
}

// ---------------- K1: s[c] = 1 + sum_f cond[f]*norm_w[f][c] ----------------
__global__ __launch_bounds__(256) void k_prep_s(const float* __restrict__ cond,
                                                const float* __restrict__ norm_w,
                                                float* __restrict__ s){
  __shared__ float red[8][33];
  int c_l = threadIdx.x & 31, fo = threadIdx.x >> 5;
  int c = blockIdx.x * 32 + c_l;
  float acc = 0.f;
  for (int f = fo * 32; f < fo * 32 + 32; ++f)
    acc = fmaf(cond[f], norm_w[f * 512 + c], acc);
  red[fo][c_l] = acc;
  __syncthreads();
  if (threadIdx.x < 32){
    float a = 0.f;
#pragma unroll
    for (int i = 0; i < 8; ++i) a += red[i][c_l];
    s[blockIdx.x * 32 + c_l] = a + 1.0f;
  }
}

// ---------------- K2: partial sum-of-squares per pixel (no atomics) ---------
// 512 blocks = 64 p-tiles x 8 c-slices -> rms_part[slice][p]
__global__ __launch_bounds__(256) void k_rms(const float* __restrict__ x,
                                             float* __restrict__ rms_part){
  __shared__ float red[4][64];
  int bp = blockIdx.x & 63, bc = blockIdx.x >> 6;
  int co = threadIdx.x >> 6, pl = threadIdx.x & 63;
  int p = bp * 64 + pl;
  float acc = 0.f;
  for (int c = bc * 64 + co; c < bc * 64 + 64; c += 4){
    float v = x[c * P_DIM + p];
    acc = fmaf(v, v, acc);
  }
  red[co][pl] = acc;
  __syncthreads();
  if (threadIdx.x < 64){
    int q = threadIdx.x;
    rms_part[bc * P_DIM + bp * 64 + q] = red[0][q] + red[1][q] + red[2][q] + red[3][q];
  }
}

// ---------------- K3: cast+transpose weights to [n][k] bf16 -----------------
__global__ __launch_bounds__(256) void k_castwT(const float* __restrict__ qkv_w,
                                                const float* __restrict__ out_w,
                                                bf16* __restrict__ qkvT,
                                                bf16* __restrict__ outT){
  __shared__ float tile[64][65];
  int bid = blockIdx.x;          // 0..191 qkv_w, 192..255 out_w
  const float* src; bf16* dst; int NW, n0, c0;
  if (bid < 192){ src = qkv_w; dst = qkvT; NW = 1536; n0 = (bid % 24) * 64; c0 = (bid / 24) * 64; }
  else { int b = bid - 192; src = out_w; dst = outT; NW = 512; n0 = (b & 7) * 64; c0 = (b >> 3) * 64; }
  int grp = threadIdx.x >> 6, lane = threadIdx.x & 63;
  for (int i = grp; i < 64; i += 4)
    tile[i][lane] = src[(c0 + i) * NW + n0 + lane];
  __syncthreads();
  for (int j = grp; j < 64; j += 4)
    dst[(n0 + j) * 512 + c0 + lane] = B16(tile[lane][j]);
}

// ---------------- K4: xn bf16 [p][c] = x[c][p]*s[c]*rsqrt(mean_ss+eps) ------
__global__ __launch_bounds__(256) void k_xnt(const float* __restrict__ x,
                                             const float* __restrict__ s,
                                             const float* __restrict__ rms_part,
                                             bf16* __restrict__ xn){
  __shared__ float tile[64][65];
  int bp = blockIdx.x & 63, bc = blockIdx.x >> 6;
  int p0 = bp * 64, c0 = bc * 64;
  int grp = threadIdx.x >> 6, lane = threadIdx.x & 63;
  for (int i = grp; i < 64; i += 4)
    tile[i][lane] = x[(c0 + i) * P_DIM + p0 + lane] * s[c0 + i];
  __syncthreads();
  for (int j = grp; j < 64; j += 4){
    float ss = 0.f;
#pragma unroll
    for (int i = 0; i < 8; ++i) ss += rms_part[i * P_DIM + p0 + j];
    float rv = rsqrtf(ss * (1.0f / 512.0f) + 1e-6f);
    xn[(size_t)(p0 + j) * 512 + c0 + lane] = B16(tile[lane][j] * rv);
  }
}

// ---------------- K5: MFMA GEMM qkv: [4096][512] @ T[1536][512] -> bf16 -----
// block tile 128x64, BK=64, 4 waves; wave w: rows w*32..w*32+31 (2 m-frags x 4 n-frags)
#define AS 72   // LDS row stride in shorts (144 B, 16B-aligned)
__global__ __launch_bounds__(256) void k_gemm_qkv(const bf16* __restrict__ Ab,
                                                  const bf16* __restrict__ BTb,
                                                  bf16* __restrict__ qkv_bf){
  __shared__ unsigned short a_t[128 * AS];
  __shared__ unsigned short b_t[64 * AS];
  const unsigned short* A  = (const unsigned short*)Ab;
  const unsigned short* BT = (const unsigned short*)BTb;
  int m0 = blockIdx.x * 128;
  int n0 = blockIdx.y * 64;
  int tid = threadIdx.x;
  int w = tid >> 6, l = tid & 63, g = l >> 4, cb = l & 15;

  f32x4 acc[2][4];
#pragma unroll
  for (int mi = 0; mi < 2; ++mi)
#pragma unroll
    for (int nj = 0; nj < 4; ++nj)
#pragma unroll
      for (int r = 0; r < 4; ++r) acc[mi][nj][r] = 0.f;

  for (int kk = 0; kk < 512; kk += 64){
    // stage A: 128 rows x 8 segs(16B) = 1024 segs, 4/thread
#pragma unroll
    for (int i = 0; i < 4; ++i){
      int sid = tid + i * 256;
      int row = sid >> 3, seg = sid & 7;
      *(uint4*)&a_t[row * AS + seg * 8] = *(const uint4*)&A[(size_t)(m0 + row) * 512 + kk + seg * 8];
    }
    // stage B: 64 rows x 8 segs = 512 segs, 2/thread
#pragma unroll
    for (int i = 0; i < 2; ++i){
      int sid = tid + i * 256;
      int row = sid >> 3, seg = sid & 7;
      *(uint4*)&b_t[row * AS + seg * 8] = *(const uint4*)&BT[(size_t)(n0 + row) * 512 + kk + seg * 8];
    }
    __syncthreads();
#pragma unroll
    for (int kc = 0; kc < 2; ++kc){
      short8 af[2];
#pragma unroll
      for (int mi = 0; mi < 2; ++mi)
        af[mi] = *(const short8*)&a_t[(w * 32 + mi * 16 + cb) * AS + kc * 32 + g * 8];
#pragma unroll
      for (int nj = 0; nj < 4; ++nj){
        short8 bfr = *(const short8*)&b_t[(nj * 16 + cb) * AS + kc * 32 + g * 8];
#pragma unroll
        for (int mi = 0; mi < 2; ++mi)
          acc[mi][nj] = __builtin_amdgcn_mfma_f32_16x16x32_bf16(af[mi], bfr, acc[mi][nj], 0, 0, 0);
      }
    }
    __syncthreads();
  }
#pragma unroll
  for (int mi = 0; mi < 2; ++mi)
#pragma unroll
    for (int nj = 0; nj < 4; ++nj){
      int col = n0 + nj * 16 + cb;
#pragma unroll
      for (int r = 0; r < 4; ++r){
        int rowg = m0 + w * 32 + mi * 16 + g * 4 + r;
        qkv_bf[(size_t)rowg * 1536 + col] = B16(acc[mi][nj][r]);
      }
    }
}

// ---------------- K6: q/k L2-norm*sqrt(scale) + rope (inline trig) ----------
__global__ __launch_bounds__(256) void k_normrope(bf16* __restrict__ qkv_bf,
                                                  const float* __restrict__ scale,
                                                  const float* __restrict__ pos){
  int u = blockIdx.x * 4 + (threadIdx.x >> 6);   // 65536 = 4096*8*2
  int d = threadIdx.x & 63;
  int p = u >> 4;
  int r = u & 15;
  int head = r >> 1;
  int qk = r & 1;
  size_t base = (size_t)p * 1536 + qk * 512 + head * 64;
  float v = F32(qkv_bf[base + d]);
  float ss = wave_sum(v * v);
  v *= sqrtf(scale[head]) * rsqrtf(ss + 1e-6f);
  float partner = __shfl_xor(v, 16, 64);
  // freqs[head][i] = exp(ln(pi) + (i*8+head)*ln(10)/64), i = (d&15)&7, axis=(d&15)>>3
  int j = d & 15;
  int axis = j >> 3, i = j & 7;
  const float LOG_PI = 1.1447298858494002f;
  const float LOG10F = 2.302585092994046f;
  float f = __expf(LOG_PI + (float)(i * 8 + head) * (LOG10F / 64.0f));
  float th = pos[(p & 1023) * 2 + axis] * f;
  float ct = __cosf(th), st = __sinf(th);
  float outv;
  if (d < 16)       outv = v * ct - partner * st;
  else if (d < 32)  outv = v * ct + partner * st;
  else              outv = v;
  qkv_bf[base + d] = B16(outv);
}

// ---------------- K7: MFMA neighborhood attention ---------------------------
// block = (8x8 patch, head); union window 14x14 = 196 keys (pad to 208 QK / 224 PV)
#define KL_S 80
#define VT_S 232
#define PP_S 232
__global__ __launch_bounds__(256) void k_attn(const bf16* __restrict__ qkv_bfp,
                                              bf16* __restrict__ o_bf){
  __shared__ unsigned short kp[208 * KL_S];     // 33280 B (>= P 64*232=29696 B)
  __shared__ unsigned short vT[64 * VT_S];      // 29696 B
  const unsigned short* qkv = (const unsigned short*)qkv_bfp;

  int bid = blockIdx.x;            // 512 = 64 patches * 8 heads
  int head = bid & 7;
  int patch = bid >> 3;
  int t = patch >> 4;
  int ph = (patch >> 2) & 3, pw = patch & 3;
  int h0 = ph * 8, w0 = pw * 8;
  int rs = min(max(h0 - 3, 0), 18);
  int cs = min(max(w0 - 3, 0), 18);
  int tbase = t << 10;
  int tid = threadIdx.x;
  int cp = tid & 31, pxg = tid >> 5;

  // stage K [px][ch], px 0..207 (>=196 zero)
  for (int i = 0; i < 26; ++i){
    int px = i * 8 + pxg;
    unsigned val = 0;
    if (px < 196){
      int rr = px / 14, cc = px - rr * 14;
      size_t pn = (size_t)(tbase + (rs + rr) * 32 + (cs + cc));
      val = *(const unsigned*)&qkv[pn * 1536 + 512 + head * 64 + cp * 2];
    }
    *(unsigned*)&kp[px * KL_S + cp * 2] = val;
  }
  // stage V^T [ch][px], px 0..223 (>=196 zero)
  for (int i = 0; i < 14; ++i){
    int pp = i * 8 + pxg;          // px pair
    int px0 = 2 * pp, px1 = px0 + 1;
    unsigned v0 = 0, v1 = 0;
    if (px0 < 196){
      int rr = px0 / 14, cc = px0 - rr * 14;
      size_t pn = (size_t)(tbase + (rs + rr) * 32 + (cs + cc));
      v0 = *(const unsigned*)&qkv[pn * 1536 + 1024 + head * 64 + cp * 2];
    }
    if (px1 < 196){
      int rr = px1 / 14, cc = px1 - rr * 14;
      size_t pn = (size_t)(tbase + (rs + rr) * 32 + (cs + cc));
      v1 = *(const unsigned*)&qkv[pn * 1536 + 1024 + head * 64 + cp * 2];
    }
    unsigned lo = (v0 & 0xffffu) | (v1 << 16);
    unsigned hi = (v0 >> 16) | (v1 & 0xffff0000u);
    *(unsigned*)&vT[(2 * cp) * VT_S + 2 * pp] = lo;
    *(unsigned*)&vT[(2 * cp + 1) * VT_S + 2 * pp] = hi;
  }

  int w = tid >> 6, l = tid & 63;
  int g = l >> 4, cb = l & 15;

  // Q A-frags straight from global: A[m=cb][k=g*8+j]
  int q_a = w * 16 + cb;
  size_t abase = (size_t)(tbase + (h0 + (q_a >> 3)) * 32 + (w0 + (q_a & 7))) * 1536 + head * 64;
  short8 qa0 = *(const short8*)&qkv[abase + g * 8];
  short8 qa1 = *(const short8*)&qkv[abase + 32 + g * 8];

  __syncthreads();

  // QK^T: 13 n-tiles of 16 keys, K=64 (2 chunks)
  f32x4 acc[13];
#pragma unroll
  for (int nt = 0; nt < 13; ++nt)
#pragma unroll
    for (int r = 0; r < 4; ++r) acc[nt][r] = 0.f;
#pragma unroll
  for (int nt = 0; nt < 13; ++nt){
    short8 kb0 = *(const short8*)&kp[(nt * 16 + cb) * KL_S + g * 8];
    short8 kb1 = *(const short8*)&kp[(nt * 16 + cb) * KL_S + 32 + g * 8];
    acc[nt] = __builtin_amdgcn_mfma_f32_16x16x32_bf16(qa0, kb0, acc[nt], 0, 0, 0);
    acc[nt] = __builtin_amdgcn_mfma_f32_16x16x32_bf16(qa1, kb1, acc[nt], 0, 0, 0);
  }
  __syncthreads();   // all waves done reading K before P overwrites kp

  // mask + softmax (row = g*4+r, col = nt*16+cb)
  int wr0[4], wc0[4];
#pragma unroll
  for (int r = 0; r < 4; ++r){
    int q_l = w * 16 + g * 4 + r;
    int hq = h0 + (q_l >> 3), wq = w0 + (q_l & 7);
    wr0[r] = min(max(hq - 3, 0), 25) - rs;
    wc0[r] = min(max(wq - 3, 0), 25) - cs;
  }
  float mx[4] = {-1e30f, -1e30f, -1e30f, -1e30f};
#pragma unroll
  for (int nt = 0; nt < 13; ++nt){
    int kg = nt * 16 + cb;
    int kr = kg / 14, kc = kg - kr * 14;
    bool kvalid = kg < 196;
#pragma unroll
    for (int r = 0; r < 4; ++r){
      bool v = kvalid && ((unsigned)(kr - wr0[r]) < 7u) && ((unsigned)(kc - wc0[r]) < 7u);
      float lg = v ? acc[nt][r] : -1e30f;
      acc[nt][r] = lg;
      mx[r] = fmaxf(mx[r], lg);
    }
  }
#pragma unroll
  for (int off = 1; off < 16; off <<= 1)
#pragma unroll
    for (int r = 0; r < 4; ++r) mx[r] = fmaxf(mx[r], __shfl_xor(mx[r], off, 64));
  float sm[4] = {0.f, 0.f, 0.f, 0.f};
#pragma unroll
  for (int nt = 0; nt < 13; ++nt)
#pragma unroll
    for (int r = 0; r < 4; ++r){
      float e = __expf(acc[nt][r] - mx[r]);
      acc[nt][r] = e;
      sm[r] += e;
    }
#pragma unroll
  for (int off = 1; off < 16; off <<= 1)
#pragma unroll
    for (int r = 0; r < 4; ++r) sm[r] += __shfl_xor(sm[r], off, 64);
  float inv[4];
#pragma unroll
  for (int r = 0; r < 4; ++r) inv[r] = 1.0f / sm[r];

  // write P (bf16) into kp region, layout [q 0..63][232], cols 208..223 zeroed
#pragma unroll
  for (int nt = 0; nt < 13; ++nt)
#pragma unroll
    for (int r = 0; r < 4; ++r)
      *reinterpret_cast<bf16*>(&kp[(w * 16 + g * 4 + r) * PP_S + nt * 16 + cb]) = B16(acc[nt][r] * inv[r]);
#pragma unroll
  for (int r = 0; r < 4; ++r)
    kp[(w * 16 + g * 4 + r) * PP_S + 208 + cb] = 0;
  __syncthreads();

  // PV: out[16q][64ch] = P[16q][224] @ V[224][64ch]
  f32x4 acc2[4];
#pragma unroll
  for (int ct = 0; ct < 4; ++ct)
#pragma unroll
    for (int r = 0; r < 4; ++r) acc2[ct][r] = 0.f;
#pragma unroll
  for (int kt = 0; kt < 7; ++kt){
    short8 pa = *(const short8*)&kp[(w * 16 + cb) * PP_S + kt * 32 + g * 8];
#pragma unroll
    for (int ct = 0; ct < 4; ++ct){
      short8 vb = *(const short8*)&vT[(ct * 16 + cb) * VT_S + kt * 32 + g * 8];
      acc2[ct] = __builtin_amdgcn_mfma_f32_16x16x32_bf16(pa, vb, acc2[ct], 0, 0, 0);
    }
  }
#pragma unroll
  for (int ct = 0; ct < 4; ++ct)
#pragma unroll
    for (int r = 0; r < 4; ++r){
      int q_l = w * 16 + g * 4 + r;
      int p = tbase + (h0 + (q_l >> 3)) * 32 + (w0 + (q_l & 7));
      o_bf[(size_t)p * 512 + head * 64 + ct * 16 + cb] = B16(acc2[ct][r]);
    }
}

// ---------------- K8: MFMA GEMM out (128x64, BK=64) + residual/transpose ----
__global__ __launch_bounds__(256) void k_gemm_out(const bf16* __restrict__ Ab,
                                                  const bf16* __restrict__ BTb,
                                                  const float* __restrict__ xres,
                                                  float* __restrict__ out){
  __shared__ unsigned short a_t[128 * AS];
  __shared__ unsigned short b_t[64 * AS];
  __shared__ float tile[64][65];
  const unsigned short* A  = (const unsigned short*)Ab;
  const unsigned short* BT = (const unsigned short*)BTb;
  int m0 = blockIdx.x * 128;   // pixels
  int n0 = blockIdx.y * 64;    // channels
  int tid = threadIdx.x;
  int w = tid >> 6, l = tid & 63, g = l >> 4, cb = l & 15;

  f32x4 acc[2][4];
#pragma unroll
  for (int mi = 0; mi < 2; ++mi)
#pragma unroll
    for (int nj = 0; nj < 4; ++nj)
#pragma unroll
      for (int r = 0; r < 4; ++r) acc[mi][nj][r] = 0.f;

  for (int kk = 0; kk < 512; kk += 64){
#pragma unroll
    for (int i = 0; i < 4; ++i){
      int sid = tid + i * 256;
      int row = sid >> 3, seg = sid & 7;
      *(uint4*)&a_t[row * AS + seg * 8] = *(const uint4*)&A[(size_t)(m0 + row) * 512 + kk + seg * 8];
    }
#pragma unroll
    for (int i = 0; i < 2; ++i){
      int sid = tid + i * 256;
      int row = sid >> 3, seg = sid & 7;
      *(uint4*)&b_t[row * AS + seg * 8] = *(const uint4*)&BT[(size_t)(n0 + row) * 512 + kk + seg * 8];
    }
    __syncthreads();
#pragma unroll
    for (int kc = 0; kc < 2; ++kc){
      short8 af[2];
#pragma unroll
      for (int mi = 0; mi < 2; ++mi)
        af[mi] = *(const short8*)&a_t[(w * 32 + mi * 16 + cb) * AS + kc * 32 + g * 8];
#pragma unroll
      for (int nj = 0; nj < 4; ++nj){
        short8 bfr = *(const short8*)&b_t[(nj * 16 + cb) * AS + kc * 32 + g * 8];
#pragma unroll
        for (int mi = 0; mi < 2; ++mi)
          acc[mi][nj] = __builtin_amdgcn_mfma_f32_16x16x32_bf16(af[mi], bfr, acc[mi][nj], 0, 0, 0);
      }
    }
    __syncthreads();
  }
  // epilogue: two 64-row halves through LDS transpose, fused residual
  int grp = tid >> 6, lane = tid & 63;
#pragma unroll
  for (int hh = 0; hh < 2; ++hh){
    __syncthreads();
    if ((w >> 1) == hh){
#pragma unroll
      for (int mi = 0; mi < 2; ++mi)
#pragma unroll
        for (int nj = 0; nj < 4; ++nj)
#pragma unroll
          for (int r = 0; r < 4; ++r)
            tile[(w & 1) * 32 + mi * 16 + g * 4 + r][nj * 16 + cb] = acc[mi][nj][r];
    }
    __syncthreads();
    for (int j2 = grp; j2 < 64; j2 += 4){
      int c = n0 + j2;
      int p = m0 + hh * 64 + lane;
      out[(size_t)c * P_DIM + p] = tile[lane][j2] + xres[(size_t)c * P_DIM + p];
    }
  }
}

extern "C" void kernel_launch(void* const* d_in, const int* in_sizes, int n_in,
                              void* d_out, int out_size, void* d_ws, size_t ws_size,
                              hipStream_t stream){
  const float* x      = (const float*)d_in[0];
  const float* pos    = (const float*)d_in[1];
  const float* cond   = (const float*)d_in[2];
  const float* norm_w = (const float*)d_in[3];
  const float* qkv_w  = (const float*)d_in[4];
  const float* scale  = (const float*)d_in[5];
  const float* out_w  = (const float*)d_in[6];
  float* out = (float*)d_out;

  char* wp = (char*)d_ws;
  auto alloc = [&](size_t bytes) -> char* {
    char* r = wp;
    wp += (bytes + 255) & ~((size_t)255);
    return r;
  };
  float* s_f      = (float*)alloc(512 * 4);
  float* rms_part = (float*)alloc(8 * 4096 * 4);
  bf16*  xn       = (bf16*) alloc((size_t)4096 * 512 * 2);
  bf16*  qkvT     = (bf16*) alloc((size_t)1536 * 512 * 2);
  bf16*  outT     = (bf16*) alloc((size_t)512 * 512 * 2);
  bf16*  qkv_bf   = (bf16*) alloc((size_t)4096 * 1536 * 2);
  bf16*  o_bf     = (bf16*) alloc((size_t)4096 * 512 * 2);

  k_prep_s  <<<16,          256, 0, stream>>>(cond, norm_w, s_f);
  k_rms     <<<512,         256, 0, stream>>>(x, rms_part);
  k_castwT  <<<256,         256, 0, stream>>>(qkv_w, out_w, qkvT, outT);
  k_xnt     <<<512,         256, 0, stream>>>(x, s_f, rms_part, xn);
  k_gemm_qkv<<<dim3(32,24), 256, 0, stream>>>(xn, qkvT, qkv_bf);
  k_normrope<<<16384,       256, 0, stream>>>(qkv_bf, scale, pos);
  k_attn    <<<512,         256, 0, stream>>>(qkv_bf, o_bf);
  k_gemm_out<<<dim3(32,8),  256, 0, stream>>>(o_bf, outT, x, out);
}

// Round 6
// 130.514 us; speedup vs baseline: 4.1924x; 1.1885x over previous
//
#include <hip/hip_runtime.h>
#include <hip/hip_bf16.h>

typedef __hip_bfloat16 bf16;
#define F32(b) __bfloat162float(b)
#define B16(f) __float2bfloat16(f)

typedef __attribute__((ext_vector_type(8))) short short8;   // MFMA A/B frag (8 bf16)
typedef __attribute__((ext_vector_type(4))) float f32x4;    // MFMA C/D frag

#define C_DIM 512
#define P_DIM 4096   // pixel p = t*1024 + h*32 + w ; x flat index = c*4096 + p

// ---------------- K1: fused prep — s[c], rms partials, weight cast/transpose
// grid 784: [0,16) prep_s ; [16,528) rms ; [528,784) castwT
__global__ __launch_bounds__(256) void k_prep(const float* __restrict__ cond,
                                              const float* __restrict__ norm_w,
                                              const float* __restrict__ x,
                                              const float* __restrict__ qkv_w,
                                              const float* __restrict__ out_w,
                                              float* __restrict__ s,
                                              float* __restrict__ rms_part,
                                              bf16* __restrict__ qkvT,
                                              bf16* __restrict__ outT){
  __shared__ float sh[64 * 65];
  int bid = blockIdx.x;
  int tid = threadIdx.x;
  if (bid < 16){
    // s[c] = 1 + sum_f cond[f]*norm_w[f][c]
    int c_l = tid & 31, fo = tid >> 5;
    int c = bid * 32 + c_l;
    float acc = 0.f;
    for (int f = fo * 32; f < fo * 32 + 32; ++f)
      acc = fmaf(cond[f], norm_w[f * 512 + c], acc);
    sh[fo * 33 + c_l] = acc;
    __syncthreads();
    if (tid < 32){
      float a = 0.f;
#pragma unroll
      for (int i = 0; i < 8; ++i) a += sh[i * 33 + tid];
      s[bid * 32 + tid] = a + 1.0f;
    }
  } else if (bid < 528){
    // partial sum-of-squares: 512 blocks = 64 p-tiles x 8 c-slices
    int b = bid - 16;
    int bp = b & 63, bc = b >> 6;
    int co = tid >> 6, pl = tid & 63;
    int p = bp * 64 + pl;
    float acc = 0.f;
    for (int c = bc * 64 + co; c < bc * 64 + 64; c += 4){
      float v = x[c * P_DIM + p];
      acc = fmaf(v, v, acc);
    }
    sh[co * 64 + pl] = acc;
    __syncthreads();
    if (tid < 64)
      rms_part[bc * P_DIM + bp * 64 + tid] = sh[tid] + sh[64 + tid] + sh[128 + tid] + sh[192 + tid];
  } else {
    // cast+transpose weights to [n][k] bf16
    int b = bid - 528;          // 0..191 qkv_w, 192..255 out_w
    const float* src; bf16* dst; int NW, n0, c0;
    if (b < 192){ src = qkv_w; dst = qkvT; NW = 1536; n0 = (b % 24) * 64; c0 = (b / 24) * 64; }
    else { int bb = b - 192; src = out_w; dst = outT; NW = 512; n0 = (bb & 7) * 64; c0 = (bb >> 3) * 64; }
    int grp = tid >> 6, lane = tid & 63;
    for (int i = grp; i < 64; i += 4)
      sh[i * 65 + lane] = src[(c0 + i) * NW + n0 + lane];
    __syncthreads();
    for (int j = grp; j < 64; j += 4)
      dst[(n0 + j) * 512 + c0 + lane] = B16(sh[lane * 65 + j]);
  }
}

// ---------------- K2: xn bf16 [p][c] = x[c][p]*s[c]*rsqrt(mean_ss+eps) ------
__global__ __launch_bounds__(256) void k_xnt(const float* __restrict__ x,
                                             const float* __restrict__ s,
                                             const float* __restrict__ rms_part,
                                             bf16* __restrict__ xn){
  __shared__ float tile[64][65];
  int bp = blockIdx.x & 63, bc = blockIdx.x >> 6;
  int p0 = bp * 64, c0 = bc * 64;
  int grp = threadIdx.x >> 6, lane = threadIdx.x & 63;
  for (int i = grp; i < 64; i += 4)
    tile[i][lane] = x[(c0 + i) * P_DIM + p0 + lane] * s[c0 + i];
  __syncthreads();
  for (int j = grp; j < 64; j += 4){
    float ss = 0.f;
#pragma unroll
    for (int i = 0; i < 8; ++i) ss += rms_part[i * P_DIM + p0 + j];
    float rv = rsqrtf(ss * (1.0f / 512.0f) + 1e-6f);
    xn[(size_t)(p0 + j) * 512 + c0 + lane] = B16(tile[lane][j] * rv);
  }
}

// ---------------- K3: MFMA GEMM qkv + fused q/k norm + rope -----------------
// block tile 128x64, BK=64, 4 waves. n-tile by: 0..7 = q heads, 8..15 = k heads,
// 16..23 = v. For q/k the 64-col tile is exactly one head's channel range, so
// the L2-norm (over 64 cols) + rope fuse into the epilogue (rope pair d/d+16
// = nj 0/1 in the same lane).
#define AS 72   // LDS row stride in shorts (144 B, 16B-aligned)
__global__ __launch_bounds__(256) void k_gemm_qkv(const bf16* __restrict__ Ab,
                                                  const bf16* __restrict__ BTb,
                                                  const float* __restrict__ scale,
                                                  const float* __restrict__ pos,
                                                  bf16* __restrict__ qkv_bf){
  __shared__ unsigned short a_t[128 * AS];
  __shared__ unsigned short b_t[64 * AS];
  const unsigned short* A  = (const unsigned short*)Ab;
  const unsigned short* BT = (const unsigned short*)BTb;
  int m0 = blockIdx.x * 128;
  int by = blockIdx.y;
  int n0 = by * 64;
  int tid = threadIdx.x;
  int w = tid >> 6, l = tid & 63, g = l >> 4, cb = l & 15;

  f32x4 acc[2][4];
#pragma unroll
  for (int mi = 0; mi < 2; ++mi)
#pragma unroll
    for (int nj = 0; nj < 4; ++nj)
#pragma unroll
      for (int r = 0; r < 4; ++r) acc[mi][nj][r] = 0.f;

  for (int kk = 0; kk < 512; kk += 64){
#pragma unroll
    for (int i = 0; i < 4; ++i){
      int sid = tid + i * 256;
      int row = sid >> 3, seg = sid & 7;
      *(uint4*)&a_t[row * AS + seg * 8] = *(const uint4*)&A[(size_t)(m0 + row) * 512 + kk + seg * 8];
    }
#pragma unroll
    for (int i = 0; i < 2; ++i){
      int sid = tid + i * 256;
      int row = sid >> 3, seg = sid & 7;
      *(uint4*)&b_t[row * AS + seg * 8] = *(const uint4*)&BT[(size_t)(n0 + row) * 512 + kk + seg * 8];
    }
    __syncthreads();
#pragma unroll
    for (int kc = 0; kc < 2; ++kc){
      short8 af[2];
#pragma unroll
      for (int mi = 0; mi < 2; ++mi)
        af[mi] = *(const short8*)&a_t[(w * 32 + mi * 16 + cb) * AS + kc * 32 + g * 8];
#pragma unroll
      for (int nj = 0; nj < 4; ++nj){
        short8 bfr = *(const short8*)&b_t[(nj * 16 + cb) * AS + kc * 32 + g * 8];
#pragma unroll
        for (int mi = 0; mi < 2; ++mi)
          acc[mi][nj] = __builtin_amdgcn_mfma_f32_16x16x32_bf16(af[mi], bfr, acc[mi][nj], 0, 0, 0);
      }
    }
    __syncthreads();
  }

  if (by < 16){
    // q/k: L2-normalize * sqrt(scale[head]) then rope over cols 0..31
    int head = by & 7;
    float sqs = sqrtf(scale[head]);
    int axis = cb >> 3, i = cb & 7;
    const float LOG_PI = 1.1447298858494002f;
    const float LOG10F = 2.302585092994046f;
    float f = __expf(LOG_PI + (float)(i * 8 + head) * (LOG10F / 64.0f));
#pragma unroll
    for (int mi = 0; mi < 2; ++mi)
#pragma unroll
      for (int r = 0; r < 4; ++r){
        float ss = 0.f;
#pragma unroll
        for (int nj = 0; nj < 4; ++nj) ss = fmaf(acc[mi][nj][r], acc[mi][nj][r], ss);
#pragma unroll
        for (int off = 1; off < 16; off <<= 1) ss += __shfl_xor(ss, off, 64);
        float fac = sqs * rsqrtf(ss + 1e-6f);
        int rowg = m0 + w * 32 + mi * 16 + g * 4 + r;
        float th = pos[(rowg & 1023) * 2 + axis] * f;
        float ct = __cosf(th), st = __sinf(th);
        float v0 = acc[mi][0][r] * fac, v1 = acc[mi][1][r] * fac;
        acc[mi][0][r] = v0 * ct - v1 * st;
        acc[mi][1][r] = v1 * ct + v0 * st;
        acc[mi][2][r] *= fac;
        acc[mi][3][r] *= fac;
      }
  }

#pragma unroll
  for (int mi = 0; mi < 2; ++mi)
#pragma unroll
    for (int nj = 0; nj < 4; ++nj){
      int col = n0 + nj * 16 + cb;
#pragma unroll
      for (int r = 0; r < 4; ++r){
        int rowg = m0 + w * 32 + mi * 16 + g * 4 + r;
        qkv_bf[(size_t)rowg * 1536 + col] = B16(acc[mi][nj][r]);
      }
    }
}

// ---------------- K4: MFMA neighborhood attention ---------------------------
// block = (8x8 patch, head); union window 14x14 = 196 keys (pad to 208 QK / 224 PV)
#define KL_S 80
#define VT_S 232
#define PP_S 232
__global__ __launch_bounds__(256) void k_attn(const bf16* __restrict__ qkv_bfp,
                                              bf16* __restrict__ o_bf){
  __shared__ unsigned short kp[208 * KL_S];     // 33280 B (>= P 64*232=29696 B)
  __shared__ unsigned short vT[64 * VT_S];      // 29696 B
  const unsigned short* qkv = (const unsigned short*)qkv_bfp;

  int bid = blockIdx.x;            // 512 = 64 patches * 8 heads
  int head = bid & 7;
  int patch = bid >> 3;
  int t = patch >> 4;
  int ph = (patch >> 2) & 3, pw = patch & 3;
  int h0 = ph * 8, w0 = pw * 8;
  int rs = min(max(h0 - 3, 0), 18);
  int cs = min(max(w0 - 3, 0), 18);
  int tbase = t << 10;
  int tid = threadIdx.x;
  int cp = tid & 31, pxg = tid >> 5;

  for (int i = 0; i < 26; ++i){
    int px = i * 8 + pxg;
    unsigned val = 0;
    if (px < 196){
      int rr = px / 14, cc = px - rr * 14;
      size_t pn = (size_t)(tbase + (rs + rr) * 32 + (cs + cc));
      val = *(const unsigned*)&qkv[pn * 1536 + 512 + head * 64 + cp * 2];
    }
    *(unsigned*)&kp[px * KL_S + cp * 2] = val;
  }
  for (int i = 0; i < 14; ++i){
    int pp = i * 8 + pxg;
    int px0 = 2 * pp, px1 = px0 + 1;
    unsigned v0 = 0, v1 = 0;
    if (px0 < 196){
      int rr = px0 / 14, cc = px0 - rr * 14;
      size_t pn = (size_t)(tbase + (rs + rr) * 32 + (cs + cc));
      v0 = *(const unsigned*)&qkv[pn * 1536 + 1024 + head * 64 + cp * 2];
    }
    if (px1 < 196){
      int rr = px1 / 14, cc = px1 - rr * 14;
      size_t pn = (size_t)(tbase + (rs + rr) * 32 + (cs + cc));
      v1 = *(const unsigned*)&qkv[pn * 1536 + 1024 + head * 64 + cp * 2];
    }
    unsigned lo = (v0 & 0xffffu) | (v1 << 16);
    unsigned hi = (v0 >> 16) | (v1 & 0xffff0000u);
    *(unsigned*)&vT[(2 * cp) * VT_S + 2 * pp] = lo;
    *(unsigned*)&vT[(2 * cp + 1) * VT_S + 2 * pp] = hi;
  }

  int w = tid >> 6, l = tid & 63;
  int g = l >> 4, cb = l & 15;

  int q_a = w * 16 + cb;
  size_t abase = (size_t)(tbase + (h0 + (q_a >> 3)) * 32 + (w0 + (q_a & 7))) * 1536 + head * 64;
  short8 qa0 = *(const short8*)&qkv[abase + g * 8];
  short8 qa1 = *(const short8*)&qkv[abase + 32 + g * 8];

  __syncthreads();

  f32x4 acc[13];
#pragma unroll
  for (int nt = 0; nt < 13; ++nt)
#pragma unroll
    for (int r = 0; r < 4; ++r) acc[nt][r] = 0.f;
#pragma unroll
  for (int nt = 0; nt < 13; ++nt){
    short8 kb0 = *(const short8*)&kp[(nt * 16 + cb) * KL_S + g * 8];
    short8 kb1 = *(const short8*)&kp[(nt * 16 + cb) * KL_S + 32 + g * 8];
    acc[nt] = __builtin_amdgcn_mfma_f32_16x16x32_bf16(qa0, kb0, acc[nt], 0, 0, 0);
    acc[nt] = __builtin_amdgcn_mfma_f32_16x16x32_bf16(qa1, kb1, acc[nt], 0, 0, 0);
  }
  __syncthreads();

  int wr0[4], wc0[4];
#pragma unroll
  for (int r = 0; r < 4; ++r){
    int q_l = w * 16 + g * 4 + r;
    int hq = h0 + (q_l >> 3), wq = w0 + (q_l & 7);
    wr0[r] = min(max(hq - 3, 0), 25) - rs;
    wc0[r] = min(max(wq - 3, 0), 25) - cs;
  }
  float mx[4] = {-1e30f, -1e30f, -1e30f, -1e30f};
#pragma unroll
  for (int nt = 0; nt < 13; ++nt){
    int kg = nt * 16 + cb;
    int kr = kg / 14, kc = kg - kr * 14;
    bool kvalid = kg < 196;
#pragma unroll
    for (int r = 0; r < 4; ++r){
      bool v = kvalid && ((unsigned)(kr - wr0[r]) < 7u) && ((unsigned)(kc - wc0[r]) < 7u);
      float lg = v ? acc[nt][r] : -1e30f;
      acc[nt][r] = lg;
      mx[r] = fmaxf(mx[r], lg);
    }
  }
#pragma unroll
  for (int off = 1; off < 16; off <<= 1)
#pragma unroll
    for (int r = 0; r < 4; ++r) mx[r] = fmaxf(mx[r], __shfl_xor(mx[r], off, 64));
  float sm[4] = {0.f, 0.f, 0.f, 0.f};
#pragma unroll
  for (int nt = 0; nt < 13; ++nt)
#pragma unroll
    for (int r = 0; r < 4; ++r){
      float e = __expf(acc[nt][r] - mx[r]);
      acc[nt][r] = e;
      sm[r] += e;
    }
#pragma unroll
  for (int off = 1; off < 16; off <<= 1)
#pragma unroll
    for (int r = 0; r < 4; ++r) sm[r] += __shfl_xor(sm[r], off, 64);
  float inv[4];
#pragma unroll
  for (int r = 0; r < 4; ++r) inv[r] = 1.0f / sm[r];

#pragma unroll
  for (int nt = 0; nt < 13; ++nt)
#pragma unroll
    for (int r = 0; r < 4; ++r)
      *reinterpret_cast<bf16*>(&kp[(w * 16 + g * 4 + r) * PP_S + nt * 16 + cb]) = B16(acc[nt][r] * inv[r]);
#pragma unroll
  for (int r = 0; r < 4; ++r)
    kp[(w * 16 + g * 4 + r) * PP_S + 208 + cb] = 0;
  __syncthreads();

  f32x4 acc2[4];
#pragma unroll
  for (int ct = 0; ct < 4; ++ct)
#pragma unroll
    for (int r = 0; r < 4; ++r) acc2[ct][r] = 0.f;
#pragma unroll
  for (int kt = 0; kt < 7; ++kt){
    short8 pa = *(const short8*)&kp[(w * 16 + cb) * PP_S + kt * 32 + g * 8];
#pragma unroll
    for (int ct = 0; ct < 4; ++ct){
      short8 vb = *(const short8*)&vT[(ct * 16 + cb) * VT_S + kt * 32 + g * 8];
      acc2[ct] = __builtin_amdgcn_mfma_f32_16x16x32_bf16(pa, vb, acc2[ct], 0, 0, 0);
    }
  }
#pragma unroll
  for (int ct = 0; ct < 4; ++ct)
#pragma unroll
    for (int r = 0; r < 4; ++r){
      int q_l = w * 16 + g * 4 + r;
      int p = tbase + (h0 + (q_l >> 3)) * 32 + (w0 + (q_l & 7));
      o_bf[(size_t)p * 512 + head * 64 + ct * 16 + cb] = B16(acc2[ct][r]);
    }
}

// ---------------- K5: MFMA GEMM out (128x64, BK=64) + residual/transpose ----
__global__ __launch_bounds__(256) void k_gemm_out(const bf16* __restrict__ Ab,
                                                  const bf16* __restrict__ BTb,
                                                  const float* __restrict__ xres,
                                                  float* __restrict__ out){
  __shared__ unsigned short a_t[128 * AS];
  __shared__ unsigned short b_t[64 * AS];
  __shared__ float tile[64][65];
  const unsigned short* A  = (const unsigned short*)Ab;
  const unsigned short* BT = (const unsigned short*)BTb;
  int m0 = blockIdx.x * 128;   // pixels
  int n0 = blockIdx.y * 64;    // channels
  int tid = threadIdx.x;
  int w = tid >> 6, l = tid & 63, g = l >> 4, cb = l & 15;

  f32x4 acc[2][4];
#pragma unroll
  for (int mi = 0; mi < 2; ++mi)
#pragma unroll
    for (int nj = 0; nj < 4; ++nj)
#pragma unroll
      for (int r = 0; r < 4; ++r) acc[mi][nj][r] = 0.f;

  for (int kk = 0; kk < 512; kk += 64){
#pragma unroll
    for (int i = 0; i < 4; ++i){
      int sid = tid + i * 256;
      int row = sid >> 3, seg = sid & 7;
      *(uint4*)&a_t[row * AS + seg * 8] = *(const uint4*)&A[(size_t)(m0 + row) * 512 + kk + seg * 8];
    }
#pragma unroll
    for (int i = 0; i < 2; ++i){
      int sid = tid + i * 256;
      int row = sid >> 3, seg = sid & 7;
      *(uint4*)&b_t[row * AS + seg * 8] = *(const uint4*)&BT[(size_t)(n0 + row) * 512 + kk + seg * 8];
    }
    __syncthreads();
#pragma unroll
    for (int kc = 0; kc < 2; ++kc){
      short8 af[2];
#pragma unroll
      for (int mi = 0; mi < 2; ++mi)
        af[mi] = *(const short8*)&a_t[(w * 32 + mi * 16 + cb) * AS + kc * 32 + g * 8];
#pragma unroll
      for (int nj = 0; nj < 4; ++nj){
        short8 bfr = *(const short8*)&b_t[(nj * 16 + cb) * AS + kc * 32 + g * 8];
#pragma unroll
        for (int mi = 0; mi < 2; ++mi)
          acc[mi][nj] = __builtin_amdgcn_mfma_f32_16x16x32_bf16(af[mi], bfr, acc[mi][nj], 0, 0, 0);
      }
    }
    __syncthreads();
  }
  int grp = tid >> 6, lane = tid & 63;
#pragma unroll
  for (int hh = 0; hh < 2; ++hh){
    __syncthreads();
    if ((w >> 1) == hh){
#pragma unroll
      for (int mi = 0; mi < 2; ++mi)
#pragma unroll
        for (int nj = 0; nj < 4; ++nj)
#pragma unroll
          for (int r = 0; r < 4; ++r)
            tile[(w & 1) * 32 + mi * 16 + g * 4 + r][nj * 16 + cb] = acc[mi][nj][r];
    }
    __syncthreads();
    for (int j2 = grp; j2 < 64; j2 += 4){
      int c = n0 + j2;
      int p = m0 + hh * 64 + lane;
      out[(size_t)c * P_DIM + p] = tile[lane][j2] + xres[(size_t)c * P_DIM + p];
    }
  }
}

extern "C" void kernel_launch(void* const* d_in, const int* in_sizes, int n_in,
                              void* d_out, int out_size, void* d_ws, size_t ws_size,
                              hipStream_t stream){
  const float* x      = (const float*)d_in[0];
  const float* pos    = (const float*)d_in[1];
  const float* cond   = (const float*)d_in[2];
  const float* norm_w = (const float*)d_in[3];
  const float* qkv_w  = (const float*)d_in[4];
  const float* scale  = (const float*)d_in[5];
  const float* out_w  = (const float*)d_in[6];
  float* out = (float*)d_out;

  char* wp = (char*)d_ws;
  auto alloc = [&](size_t bytes) -> char* {
    char* r = wp;
    wp += (bytes + 255) & ~((size_t)255);
    return r;
  };
  float* s_f      = (float*)alloc(512 * 4);
  float* rms_part = (float*)alloc(8 * 4096 * 4);
  bf16*  xn       = (bf16*) alloc((size_t)4096 * 512 * 2);
  bf16*  qkvT     = (bf16*) alloc((size_t)1536 * 512 * 2);
  bf16*  outT     = (bf16*) alloc((size_t)512 * 512 * 2);
  bf16*  qkv_bf   = (bf16*) alloc((size_t)4096 * 1536 * 2);
  bf16*  o_bf     = (bf16*) alloc((size_t)4096 * 512 * 2);

  k_prep    <<<784,         256, 0, stream>>>(cond, norm_w, x, qkv_w, out_w,
                                              s_f, rms_part, qkvT, outT);
  k_xnt     <<<512,         256, 0, stream>>>(x, s_f, rms_part, xn);
  k_gemm_qkv<<<dim3(32,24), 256, 0, stream>>>(xn, qkvT, scale, pos, qkv_bf);
  k_attn    <<<512,         256, 0, stream>>>(qkv_bf, o_bf);
  k_gemm_out<<<dim3(32,8),  256, 0, stream>>>(o_bf, outT, x, out);
}